// Round 3
// baseline (994.667 us; speedup 1.0000x reference)
//
#include <hip/hip_runtime.h>
#include <cstdint>
#include <cstddef>

#define B_ROWS 8192
#define D_DIM  1024
#define H_DIM  4096
#define O_DIM  1024
#define E_NUM  3

typedef __attribute__((ext_vector_type(4))) float f4;
typedef __attribute__((ext_vector_type(2))) float f2;
typedef __attribute__((ext_vector_type(8))) _Float16 half8;

__device__ __forceinline__ unsigned short f2h_bits(float f) {
  _Float16 h = (_Float16)f;
  return __builtin_bit_cast(unsigned short, h);
}

// async global->LDS, 16B per lane. LDS dest = wave-uniform base + lane*16.
__device__ __forceinline__ void async16(const void* g, void* l) {
  __builtin_amdgcn_global_load_lds(
      (const __attribute__((address_space(1))) unsigned int*)g,
      (__attribute__((address_space(3))) unsigned int*)l, 16, 0, 0);
}

// ---------------- cast x (fp32 -> f16), 8 elems/thread ----------------
__global__ __launch_bounds__(256) void k_cast_x(const float* __restrict__ in,
                                                unsigned short* __restrict__ out) {
  size_t i = (size_t)blockIdx.x * 256 + threadIdx.x;
  const f4* p = (const f4*)in;
  f4 a = p[2 * i], b = p[2 * i + 1];
  half8 h;
#pragma unroll
  for (int j = 0; j < 4; ++j) { h[j] = (_Float16)a[j]; h[4 + j] = (_Float16)b[j]; }
  *(half8*)(out + 8 * i) = h;
}

// ------------- transpose + cast: in[e][R][C] f32 -> out[e][C][R] f16 -------------
__global__ __launch_bounds__(256) void k_transpose_cast(const float* __restrict__ in,
                                                        unsigned short* __restrict__ out,
                                                        int R, int C) {
  __shared__ float tile[32][33];
  const size_t eoff = (size_t)blockIdx.z * R * C;
  const float* I = in + eoff;
  unsigned short* O = out + eoff;
  int c0 = blockIdx.x * 32, r0 = blockIdx.y * 32;
  int tx = threadIdx.x & 31, ty = threadIdx.x >> 5;
#pragma unroll
  for (int i = 0; i < 4; ++i)
    tile[ty + 8 * i][tx] = I[(size_t)(r0 + ty + 8 * i) * C + c0 + tx];
  __syncthreads();
#pragma unroll
  for (int i = 0; i < 4; ++i)
    O[(size_t)(c0 + ty + 8 * i) * R + r0 + tx] = f2h_bits(tile[tx][ty + 8 * i]);
}

// ------------- fp32 GEMM + bias + relu (gating layers), 32x64 tile -------------
// 256 thr, 2x4 microtile; grid.y covers M/32 -> 2+ blocks/CU for latency hiding.
__global__ __launch_bounds__(256) void k_gemm_f32(const float* __restrict__ A,
                                                  const float* __restrict__ Bm,
                                                  const float* __restrict__ bias,
                                                  float* __restrict__ C,
                                                  int N, int K) {
  __shared__ float sAT[16][36];  // [k][m]
  __shared__ float sB[16][68];   // [k][n]
  const int t = threadIdx.x;
  const int tx = t & 15, ty = t >> 4;
  const int m0 = blockIdx.y * 32, n0 = blockIdx.x * 64;
  float acc[2][4] = {};
  for (int k0 = 0; k0 < K; k0 += 16) {
    __syncthreads();
    {
      int r = t >> 4, c = t & 15;                 // A: 32x16 = 512 elems, 2/thread
      sAT[c][r] = A[(size_t)(m0 + r) * K + (k0 + c)];
      int r2 = (t + 256) >> 4, c2 = (t + 256) & 15;
      sAT[c2][r2] = A[(size_t)(m0 + r2) * K + (k0 + c2)];
#pragma unroll
      for (int i = 0; i < 4; ++i) {               // B: 16x64 = 1024, 4/thread
        int idx = t + i * 256;
        int rb = idx >> 6, cb = idx & 63;
        sB[rb][cb] = Bm[(size_t)(k0 + rb) * N + (n0 + cb)];
      }
    }
    __syncthreads();
#pragma unroll
    for (int kk = 0; kk < 16; ++kk) {
      f2 av = *(const f2*)&sAT[kk][ty * 2];
      f4 bv = *(const f4*)&sB[kk][tx * 4];
#pragma unroll
      for (int i = 0; i < 2; ++i)
#pragma unroll
        for (int j = 0; j < 4; ++j)
          acc[i][j] = fmaf(av[i], bv[j], acc[i][j]);
    }
  }
#pragma unroll
  for (int i = 0; i < 2; ++i) {
    int row = m0 + ty * 2 + i;
    f4 v;
#pragma unroll
    for (int j = 0; j < 4; ++j)
      v[j] = fmaxf(acc[i][j] + bias[n0 + tx * 4 + j], 0.f);
    *(f4*)&C[(size_t)row * N + n0 + tx * 4] = v;
  }
}

// ------------- gating layer 3 + softmax + top-2 + renorm -------------
__global__ __launch_bounds__(256) void k_gate_topk(const float* __restrict__ h2,
                                                   const float* __restrict__ gw3,
                                                   const float* __restrict__ gb3,
                                                   float* __restrict__ gates,
                                                   float* __restrict__ combine) {
  const int lane = threadIdx.x & 63;
  const int row = blockIdx.x * 4 + (threadIdx.x >> 6);
  const float* h = h2 + (size_t)row * 128;
  float h0 = h[lane], h1 = h[lane + 64];
  float l0 = h0 * gw3[lane * 3 + 0] + h1 * gw3[(lane + 64) * 3 + 0];
  float l1 = h0 * gw3[lane * 3 + 1] + h1 * gw3[(lane + 64) * 3 + 1];
  float l2 = h0 * gw3[lane * 3 + 2] + h1 * gw3[(lane + 64) * 3 + 2];
#pragma unroll
  for (int off = 32; off > 0; off >>= 1) {
    l0 += __shfl_down(l0, off);
    l1 += __shfl_down(l1, off);
    l2 += __shfl_down(l2, off);
  }
  if (lane == 0) {
    float g0 = l0 + gb3[0], g1v = l1 + gb3[1], g2v = l2 + gb3[2];
    float mx = fmaxf(g0, fmaxf(g1v, g2v));
    float e0 = expf(g0 - mx), e1 = expf(g1v - mx), e2 = expf(g2v - mx);
    float inv = 1.f / (e0 + e1 + e2);
    float p0 = e0 * inv, p1 = e1 * inv, p2 = e2 * inv;
    gates[row * 3 + 0] = p0; gates[row * 3 + 1] = p1; gates[row * 3 + 2] = p2;
    // exclude argmin; '<=' so ties exclude the HIGHER index (lax.top_k tie rule)
    int amin = 0; float pm = p0;
    if (p1 <= pm) { pm = p1; amin = 1; }
    if (p2 <= pm) { pm = p2; amin = 2; }
    float denom = (p0 + p1 + p2) - pm;
    combine[row * 3 + 0] = (amin == 0) ? 0.f : p0 / denom;
    combine[row * 3 + 1] = (amin == 1) ? 0.f : p1 / denom;
    combine[row * 3 + 2] = (amin == 2) ? 0.f : p2 / denom;
  }
}

// ---------------- expert GEMM1: ehs = f16(c * relu(x @ w1 + eb1)) ----------------
// 128x128 tile, BK=64, 4 waves (2x2), 16x16x32 f16 MFMA, async LDS staging,
// XOR-swizzled LDS (16B blocks, j ^= row&7) so ds_read_b128 is 2-way max.
__global__ __launch_bounds__(256) void k_expert_h(const unsigned short* __restrict__ Xh,
                                                  const unsigned short* __restrict__ W1T,
                                                  const float* __restrict__ combine,
                                                  const float* __restrict__ eb1,
                                                  unsigned short* __restrict__ EHS,
                                                  int Brows) {
  constexpr int K = D_DIM;  // 1024
  const int e = blockIdx.z;
  const int m0 = blockIdx.y * 128, n0 = blockIdx.x * 128;
  __shared__ __align__(16) char smem[32768];
  __shared__ float sC[128];
  char* sA = smem;
  char* sB = smem + 16384;
  const int t = threadIdx.x;
  if (t < 128) sC[t] = combine[(size_t)(m0 + t) * 3 + e];

  const unsigned short* aptr[4];
  const unsigned short* bptr[4];
  int soff[4];
#pragma unroll
  for (int i = 0; i < 4; ++i) {
    int sa = t + i * 256;
    int row = sa >> 3;
    int j = (sa & 7) ^ (row & 7);
    soff[i] = sa * 16;
    aptr[i] = Xh + (size_t)(m0 + row) * K + j * 8;
    bptr[i] = W1T + (size_t)e * H_DIM * K + (size_t)(n0 + row) * K + j * 8;
  }
  const int lane = t & 63;
  const int wm = (t >> 6) & 1, wn = t >> 7;
  const int quad = lane >> 4, l16 = lane & 15;
  int offA[4][2], offB[4][2];
#pragma unroll
  for (int mt = 0; mt < 4; ++mt) {
    int ra = wm * 64 + mt * 16 + l16;
    int rb = wn * 64 + mt * 16 + l16;
#pragma unroll
    for (int s = 0; s < 2; ++s) {
      offA[mt][s] = ra * 128 + (((s * 4 + quad) ^ (ra & 7)) * 16);
      offB[mt][s] = rb * 128 + (((s * 4 + quad) ^ (rb & 7)) * 16);
    }
  }
  f4 acc[4][4] = {};
  for (int k0 = 0; k0 < K; k0 += 64) {
#pragma unroll
    for (int i = 0; i < 4; ++i) {
      async16(aptr[i] + k0, sA + soff[i]);
      async16(bptr[i] + k0, sB + soff[i]);
    }
    __syncthreads();
#pragma unroll
    for (int s = 0; s < 2; ++s) {
      half8 a[4], b[4];
#pragma unroll
      for (int mt = 0; mt < 4; ++mt) a[mt] = *(const half8*)(sA + offA[mt][s]);
#pragma unroll
      for (int nt = 0; nt < 4; ++nt) b[nt] = *(const half8*)(sB + offB[nt][s]);
#pragma unroll
      for (int mt = 0; mt < 4; ++mt)
#pragma unroll
        for (int nt = 0; nt < 4; ++nt)
          acc[mt][nt] = __builtin_amdgcn_mfma_f32_16x16x32_f16(a[mt], b[nt], acc[mt][nt], 0, 0, 0);
    }
    __syncthreads();
  }
  const float* bias = eb1 + (size_t)e * H_DIM;
  unsigned short* out = EHS + (size_t)e * Brows * H_DIM;
#pragma unroll
  for (int nt = 0; nt < 4; ++nt) {
    int col = n0 + wn * 64 + nt * 16 + l16;
    float bb = bias[col];
#pragma unroll
    for (int mt = 0; mt < 4; ++mt) {
#pragma unroll
      for (int r = 0; r < 4; ++r) {
        int rloc = wm * 64 + mt * 16 + quad * 4 + r;
        float v = fmaxf(acc[mt][nt][r] + bb, 0.f) * sC[rloc];
        out[(size_t)(m0 + rloc) * H_DIM + col] = f2h_bits(v);
      }
    }
  }
}

// ------- expert GEMM2, split by expert: out += ehs_e @ w2_e + c_e*eb2_e --------
// blockIdx.z = expert; fp32 atomicAdd into memset-zeroed OUT. Grid x3 vs fused
// e-loop -> 3-6 blocks/CU instead of 1-2 (fixes the 11% occupancy starvation).
__global__ __launch_bounds__(256) void k_expert_o(const unsigned short* __restrict__ EHS,
                                                  const unsigned short* __restrict__ W2T,
                                                  const float* __restrict__ combine,
                                                  const float* __restrict__ eb2,
                                                  float* __restrict__ OUT,
                                                  int Brows) {
  constexpr int K = H_DIM;  // 4096
  const int e = blockIdx.z;
  const int m0 = blockIdx.y * 128, n0 = blockIdx.x * 128;
  __shared__ __align__(16) char smem[32768];
  __shared__ float sC[128];
  char* sA = smem;
  char* sB = smem + 16384;
  const int t = threadIdx.x;
  if (t < 128) sC[t] = combine[(size_t)(m0 + t) * 3 + e];

  const unsigned short* ap[4];
  const unsigned short* bp[4];
  int soff[4];
  const unsigned short* Ab = EHS + (size_t)e * Brows * H_DIM + (size_t)m0 * K;
  const unsigned short* Bb = W2T + (size_t)e * O_DIM * H_DIM + (size_t)n0 * K;
#pragma unroll
  for (int i = 0; i < 4; ++i) {
    int sa = t + i * 256;
    int row = sa >> 3;
    int j = (sa & 7) ^ (row & 7);
    soff[i] = sa * 16;
    ap[i] = Ab + (size_t)row * K + j * 8;
    bp[i] = Bb + (size_t)row * K + j * 8;
  }
  const int lane = t & 63;
  const int wm = (t >> 6) & 1, wn = t >> 7;
  const int quad = lane >> 4, l16 = lane & 15;
  int offA[4][2], offB[4][2];
#pragma unroll
  for (int mt = 0; mt < 4; ++mt) {
    int ra = wm * 64 + mt * 16 + l16;
    int rb = wn * 64 + mt * 16 + l16;
#pragma unroll
    for (int s = 0; s < 2; ++s) {
      offA[mt][s] = ra * 128 + (((s * 4 + quad) ^ (ra & 7)) * 16);
      offB[mt][s] = rb * 128 + (((s * 4 + quad) ^ (rb & 7)) * 16);
    }
  }
  f4 acc[4][4] = {};
  for (int k0 = 0; k0 < K; k0 += 64) {
#pragma unroll
    for (int i = 0; i < 4; ++i) {
      async16(ap[i] + k0, sA + soff[i]);
      async16(bp[i] + k0, sB + soff[i]);
    }
    __syncthreads();
#pragma unroll
    for (int s = 0; s < 2; ++s) {
      half8 a[4], b[4];
#pragma unroll
      for (int mt = 0; mt < 4; ++mt) a[mt] = *(const half8*)(sA + offA[mt][s]);
#pragma unroll
      for (int nt = 0; nt < 4; ++nt) b[nt] = *(const half8*)(sB + offB[nt][s]);
#pragma unroll
      for (int mt = 0; mt < 4; ++mt)
#pragma unroll
        for (int nt = 0; nt < 4; ++nt)
          acc[mt][nt] = __builtin_amdgcn_mfma_f32_16x16x32_f16(a[mt], b[nt], acc[mt][nt], 0, 0, 0);
    }
    __syncthreads();
  }
  const float* bias = eb2 + (size_t)e * O_DIM;
#pragma unroll
  for (int nt = 0; nt < 4; ++nt) {
    int col = n0 + wn * 64 + nt * 16 + l16;
    float bb = bias[col];
#pragma unroll
    for (int mt = 0; mt < 4; ++mt) {
#pragma unroll
      for (int r = 0; r < 4; ++r) {
        int rloc = wm * 64 + mt * 16 + quad * 4 + r;
        float v = acc[mt][nt][r] + sC[rloc] * bb;
        atomicAdd(&OUT[(size_t)(m0 + rloc) * O_DIM + col], v);
      }
    }
  }
}

extern "C" void kernel_launch(void* const* d_in, const int* in_sizes, int n_in,
                              void* d_out, int out_size, void* d_ws, size_t ws_size,
                              hipStream_t stream) {
  const float* x   = (const float*)d_in[0];
  const float* gw1 = (const float*)d_in[1];
  const float* gb1 = (const float*)d_in[2];
  const float* gw2 = (const float*)d_in[3];
  const float* gb2 = (const float*)d_in[4];
  const float* gw3 = (const float*)d_in[5];
  const float* gb3 = (const float*)d_in[6];
  const float* ew1 = (const float*)d_in[7];
  const float* eb1 = (const float*)d_in[8];
  const float* ew2 = (const float*)d_in[9];
  const float* eb2 = (const float*)d_in[10];
  float* out = (float*)d_out;
  float* gates = out + (size_t)B_ROWS * O_DIM;

  char* ws = (char*)d_ws;
  size_t off = 0;
  auto take = [&](size_t bytes) -> char* {
    char* p = ws + off;
    off += (bytes + 255) & ~(size_t)255;
    return p;
  };
  // fixed region: 67.4 MB
  unsigned short* xh  = (unsigned short*)take((size_t)B_ROWS * D_DIM * 2);        // 16.8 MB
  unsigned short* w1t = (unsigned short*)take((size_t)E_NUM * H_DIM * D_DIM * 2); // 25.2 MB
  unsigned short* w2t = (unsigned short*)take((size_t)E_NUM * O_DIM * H_DIM * 2); // 25.2 MB
  float* comb = (float*)take((size_t)B_ROWS * 3 * 4);                             // 0.1 MB

  // chunked region: sized to whatever workspace remains.
  // per-row bytes: ehs 3*4096*2 + g1 256*4 + h2 128*4 = 26112
  char* rest = ws + off;
  size_t rest_sz = (ws_size > off) ? (ws_size - off) : 0;
  int Bc = (int)((rest_sz / 26112) / 128 * 128);
  if (Bc > B_ROWS) Bc = B_ROWS;
  if (Bc < 128) Bc = 128;  // below this the workspace is fundamentally too small

  unsigned short* ehs = (unsigned short*)rest;
  float* g1 = (float*)(rest + (size_t)E_NUM * Bc * H_DIM * 2);
  float* h2 = (float*)((char*)g1 + (size_t)Bc * 256 * 4);

  // zero `out` — k_expert_o accumulates per-expert partials with atomicAdd
  hipMemsetAsync(out, 0, (size_t)B_ROWS * O_DIM * 4, stream);

  // precision-insensitive pre-pass: f16 casts/transposes
  k_cast_x<<<dim3(B_ROWS * D_DIM / (256 * 8)), 256, 0, stream>>>(x, xh);
  k_transpose_cast<<<dim3(H_DIM / 32, D_DIM / 32, E_NUM), 256, 0, stream>>>(ew1, w1t, D_DIM, H_DIM);
  k_transpose_cast<<<dim3(O_DIM / 32, H_DIM / 32, E_NUM), 256, 0, stream>>>(ew2, w2t, H_DIM, O_DIM);

  for (int row0 = 0; row0 < B_ROWS; row0 += Bc) {
    int rows = B_ROWS - row0;
    if (rows > Bc) rows = Bc;
    // gating in fp32 (top-k selection must track the fp32 reference)
    k_gemm_f32<<<dim3(256 / 64, rows / 32), 256, 0, stream>>>(
        x + (size_t)row0 * D_DIM, gw1, gb1, g1, 256, D_DIM);
    k_gemm_f32<<<dim3(128 / 64, rows / 32), 256, 0, stream>>>(
        g1, gw2, gb2, h2, 128, 256);
    k_gate_topk<<<dim3(rows / 4), 256, 0, stream>>>(
        h2, gw3, gb3, gates + (size_t)row0 * 3, comb + (size_t)row0 * 3);
    // experts in f16 MFMA
    k_expert_h<<<dim3(H_DIM / 128, rows / 128, E_NUM), 256, 0, stream>>>(
        xh + (size_t)row0 * D_DIM, w1t, comb + (size_t)row0 * 3, eb1, ehs, rows);
    k_expert_o<<<dim3(O_DIM / 128, rows / 128, E_NUM), 256, 0, stream>>>(
        ehs, w2t, comb + (size_t)row0 * 3, eb2, out + (size_t)row0 * O_DIM, rows);
  }
}

// Round 4
// 812.046 us; speedup vs baseline: 1.2249x; 1.2249x over previous
//
#include <hip/hip_runtime.h>
#include <cstdint>
#include <cstddef>

#define B_ROWS 8192
#define D_DIM  1024
#define H_DIM  4096
#define O_DIM  1024
#define E_NUM  3
#define K2     (2 * H_DIM)          // per-slot K in expert GEMM2
#define MT_MAX 66                   // worst-case m-tiles: 64 + 2 (128-pad per bucket)
#define SLOT_MAX (MT_MAX * 128)

typedef __attribute__((ext_vector_type(4))) float f4;
typedef __attribute__((ext_vector_type(8))) _Float16 half8;

__device__ __forceinline__ unsigned short f2h_bits(float f) {
  _Float16 h = (_Float16)f;
  return __builtin_bit_cast(unsigned short, h);
}

// async global->LDS, 16B per lane. LDS dest = wave-uniform base + lane*16.
__device__ __forceinline__ void async16(const void* g, void* l) {
  __builtin_amdgcn_global_load_lds(
      (const __attribute__((address_space(1))) unsigned int*)g,
      (__attribute__((address_space(3))) unsigned int*)l, 16, 0, 0);
}

// ---------------- cast x (fp32 -> f16), 8 elems/thread ----------------
__global__ __launch_bounds__(256) void k_cast_x(const float* __restrict__ in,
                                                unsigned short* __restrict__ out) {
  size_t i = (size_t)blockIdx.x * 256 + threadIdx.x;
  const f4* p = (const f4*)in;
  f4 a = p[2 * i], b = p[2 * i + 1];
  half8 h;
#pragma unroll
  for (int j = 0; j < 4; ++j) { h[j] = (_Float16)a[j]; h[4 + j] = (_Float16)b[j]; }
  *(half8*)(out + 8 * i) = h;
}

// ------------- transpose + cast: in[e][R][C] f32 -> out[e][C][R] f16 -------------
__global__ __launch_bounds__(256) void k_transpose_cast(const float* __restrict__ in,
                                                        unsigned short* __restrict__ out,
                                                        int R, int C) {
  __shared__ float tile[32][33];
  const size_t eoff = (size_t)blockIdx.z * R * C;
  const float* I = in + eoff;
  unsigned short* O = out + eoff;
  int c0 = blockIdx.x * 32, r0 = blockIdx.y * 32;
  int tx = threadIdx.x & 31, ty = threadIdx.x >> 5;
#pragma unroll
  for (int i = 0; i < 4; ++i)
    tile[ty + 8 * i][tx] = I[(size_t)(r0 + ty + 8 * i) * C + c0 + tx];
  __syncthreads();
#pragma unroll
  for (int i = 0; i < 4; ++i)
    O[(size_t)(c0 + ty + 8 * i) * R + r0 + tx] = f2h_bits(tile[tx][ty + 8 * i]);
}

// ------------- fp32 GEMM + bias + relu (gating layers), 64x64 tile (R2 version) -------------
__global__ __launch_bounds__(256) void k_gemm_f32(const float* __restrict__ A,
                                                  const float* __restrict__ Bm,
                                                  const float* __restrict__ bias,
                                                  float* __restrict__ C,
                                                  int N, int K) {
  __shared__ float sAT[16][68];
  __shared__ float sB[16][68];
  const int t = threadIdx.x;
  const int tx = t & 15, ty = t >> 4;
  const int m0 = blockIdx.y * 64, n0 = blockIdx.x * 64;
  float acc[4][4] = {};
  for (int k0 = 0; k0 < K; k0 += 16) {
    __syncthreads();
#pragma unroll
    for (int i = 0; i < 4; ++i) {
      int idx = t + i * 256;
      int r = idx >> 4, c = idx & 15;
      sAT[c][r] = A[(size_t)(m0 + r) * K + (k0 + c)];
      int rb = idx >> 6, cb = idx & 63;
      sB[rb][cb] = Bm[(size_t)(k0 + rb) * N + (n0 + cb)];
    }
    __syncthreads();
#pragma unroll
    for (int kk = 0; kk < 16; ++kk) {
      f4 av = *(const f4*)&sAT[kk][ty * 4];
      f4 bv = *(const f4*)&sB[kk][tx * 4];
#pragma unroll
      for (int i = 0; i < 4; ++i)
#pragma unroll
        for (int j = 0; j < 4; ++j)
          acc[i][j] = fmaf(av[i], bv[j], acc[i][j]);
    }
  }
#pragma unroll
  for (int i = 0; i < 4; ++i) {
    int row = m0 + ty * 4 + i;
    f4 v;
#pragma unroll
    for (int j = 0; j < 4; ++j)
      v[j] = fmaxf(acc[i][j] + bias[n0 + tx * 4 + j], 0.f);
    *(f4*)&C[(size_t)row * N + n0 + tx * 4] = v;
  }
}

// ------------- gating layer 3 + softmax + top-2 + renorm + bucket id -------------
__global__ __launch_bounds__(256) void k_gate_topk(const float* __restrict__ h2,
                                                   const float* __restrict__ gw3,
                                                   const float* __restrict__ gb3,
                                                   float* __restrict__ gates,
                                                   float* __restrict__ combine,
                                                   int* __restrict__ bucket) {
  const int lane = threadIdx.x & 63;
  const int row = blockIdx.x * 4 + (threadIdx.x >> 6);
  const float* h = h2 + (size_t)row * 128;
  float h0 = h[lane], h1 = h[lane + 64];
  float l0 = h0 * gw3[lane * 3 + 0] + h1 * gw3[(lane + 64) * 3 + 0];
  float l1 = h0 * gw3[lane * 3 + 1] + h1 * gw3[(lane + 64) * 3 + 1];
  float l2 = h0 * gw3[lane * 3 + 2] + h1 * gw3[(lane + 64) * 3 + 2];
#pragma unroll
  for (int off = 32; off > 0; off >>= 1) {
    l0 += __shfl_down(l0, off);
    l1 += __shfl_down(l1, off);
    l2 += __shfl_down(l2, off);
  }
  if (lane == 0) {
    float g0 = l0 + gb3[0], g1v = l1 + gb3[1], g2v = l2 + gb3[2];
    float mx = fmaxf(g0, fmaxf(g1v, g2v));
    float e0 = expf(g0 - mx), e1 = expf(g1v - mx), e2 = expf(g2v - mx);
    float inv = 1.f / (e0 + e1 + e2);
    float p0 = e0 * inv, p1 = e1 * inv, p2 = e2 * inv;
    gates[row * 3 + 0] = p0; gates[row * 3 + 1] = p1; gates[row * 3 + 2] = p2;
    // exclude argmin; '<=' so ties exclude the HIGHER index (lax.top_k tie rule)
    int amin = 0; float pm = p0;
    if (p1 <= pm) { pm = p1; amin = 1; }
    if (p2 <= pm) { pm = p2; amin = 2; }
    float denom = (p0 + p1 + p2) - pm;
    combine[row * 3 + 0] = (amin == 0) ? 0.f : p0 / denom;
    combine[row * 3 + 1] = (amin == 1) ? 0.f : p1 / denom;
    combine[row * 3 + 2] = (amin == 2) ? 0.f : p2 / denom;
    bucket[row] = amin;  // bucket = excluded expert
  }
}

// ------------- routing: count / bases / scatter (ballot-aggregated atomics) -------------
__global__ __launch_bounds__(256) void k_count(const int* __restrict__ bucket,
                                               int* __restrict__ cnt) {
  int row = blockIdx.x * 256 + threadIdx.x;
  int b = bucket[row];
  int lane = threadIdx.x & 63;
#pragma unroll
  for (int bid = 0; bid < 3; ++bid) {
    unsigned long long m = __ballot(b == bid);
    if (m && b == bid) {
      int prefix = __popcll(m & ((1ull << lane) - 1));
      if (prefix == 0) atomicAdd(&cnt[bid], __popcll(m));
    }
  }
}

// meta[0..3] = tile-base prefix (tiles_b = ceil(cnt_b/128)); also zeroes cnt2.
__global__ void k_meta(const int* __restrict__ cnt, int* __restrict__ meta,
                       int* __restrict__ cnt2) {
  int t0 = (cnt[0] + 127) >> 7;
  int t1 = (cnt[1] + 127) >> 7;
  int t2 = (cnt[2] + 127) >> 7;
  meta[0] = 0; meta[1] = t0; meta[2] = t0 + t1; meta[3] = t0 + t1 + t2;
  cnt2[0] = 0; cnt2[1] = 0; cnt2[2] = 0;
}

__global__ __launch_bounds__(256) void k_scatter(const int* __restrict__ bucket,
                                                 const int* __restrict__ meta,
                                                 int* __restrict__ cnt2,
                                                 int* __restrict__ sorted) {
  int row = blockIdx.x * 256 + threadIdx.x;
  int b = bucket[row];
  int lane = threadIdx.x & 63;
#pragma unroll
  for (int bid = 0; bid < 3; ++bid) {
    unsigned long long m = __ballot(b == bid);
    if (m) {
      int cntm = __popcll(m);
      int leader = __ffsll((unsigned long long)m) - 1;
      int base = 0;
      if (lane == leader) base = atomicAdd(&cnt2[bid], cntm);
      base = __shfl(base, leader);
      if (b == bid) {
        int prefix = __popcll(m & ((1ull << lane) - 1));
        sorted[meta[bid] * 128 + base + prefix] = row;
      }
    }
  }
}

// experts for bucket b (b = excluded expert)
__device__ __forceinline__ void bucket_experts(int b, int& ea, int& eb) {
  ea = (b == 0) ? 1 : 0;
  eb = (b == 2) ? 1 : 2;
}

// ---------------- expert GEMM1 (routed): ehs[slot][z] = f16(c * relu(x[r] @ w1_e + eb1_e)) ----------------
// grid (MT_MAX, H/128, 2); blockIdx.x = m-tile (fast-varying -> B-slice L2 reuse).
__global__ __launch_bounds__(256) void k_expert_h(const unsigned short* __restrict__ Xh,
                                                  const unsigned short* __restrict__ W1T,
                                                  const float* __restrict__ combine,
                                                  const float* __restrict__ eb1,
                                                  const int* __restrict__ sorted,
                                                  const int* __restrict__ meta,
                                                  unsigned short* __restrict__ EHS) {
  constexpr int K = D_DIM;  // 1024
  const int mt = blockIdx.x;
  const int tb1 = meta[1], tb2 = meta[2], tb3 = meta[3];
  if (mt >= tb3) return;
  const int b = (mt >= tb2) ? 2 : (mt >= tb1) ? 1 : 0;
  int ea, ebx; bucket_experts(b, ea, ebx);
  const int z = blockIdx.z;
  const int e = z ? ebx : ea;
  const int slot0 = ((b == 0) ? 0 : (b == 1) ? tb1 : tb2) * 128 + (mt - ((b == 0) ? 0 : (b == 1) ? tb1 : tb2)) * 128;
  const int n0 = blockIdx.y * 128;

  __shared__ __align__(16) char smem[32768];
  __shared__ float sC[128];
  char* sA = smem;
  char* sB = smem + 16384;
  const int t = threadIdx.x;
  if (t < 128) {
    int r = sorted[slot0 + t];
    sC[t] = (r < 0) ? 0.f : combine[(size_t)r * 3 + e];
  }

  const unsigned short* aptr[4];
  const unsigned short* bptr[4];
  int soff[4];
#pragma unroll
  for (int i = 0; i < 4; ++i) {
    int sa = t + i * 256;
    int row = sa >> 3;
    int j = (sa & 7) ^ (row & 7);
    soff[i] = sa * 16;
    int r = sorted[slot0 + row];
    int rr = (r < 0) ? 0 : r;
    aptr[i] = Xh + (size_t)rr * K + j * 8;
    bptr[i] = W1T + (size_t)e * H_DIM * K + (size_t)(n0 + row) * K + j * 8;
  }
  const int lane = t & 63;
  const int wm = (t >> 6) & 1, wn = t >> 7;
  const int quad = lane >> 4, l16 = lane & 15;
  int offA[4][2], offB[4][2];
#pragma unroll
  for (int mtile = 0; mtile < 4; ++mtile) {
    int ra = wm * 64 + mtile * 16 + l16;
    int rb = wn * 64 + mtile * 16 + l16;
#pragma unroll
    for (int s = 0; s < 2; ++s) {
      offA[mtile][s] = ra * 128 + (((s * 4 + quad) ^ (ra & 7)) * 16);
      offB[mtile][s] = rb * 128 + (((s * 4 + quad) ^ (rb & 7)) * 16);
    }
  }
  f4 acc[4][4] = {};
  for (int k0 = 0; k0 < K; k0 += 64) {
#pragma unroll
    for (int i = 0; i < 4; ++i) {
      async16(aptr[i] + k0, sA + soff[i]);
      async16(bptr[i] + k0, sB + soff[i]);
    }
    __syncthreads();
#pragma unroll
    for (int s = 0; s < 2; ++s) {
      half8 a[4], bfr[4];
#pragma unroll
      for (int i = 0; i < 4; ++i) a[i] = *(const half8*)(sA + offA[i][s]);
#pragma unroll
      for (int i = 0; i < 4; ++i) bfr[i] = *(const half8*)(sB + offB[i][s]);
#pragma unroll
      for (int i = 0; i < 4; ++i)
#pragma unroll
        for (int jn = 0; jn < 4; ++jn)
          acc[i][jn] = __builtin_amdgcn_mfma_f32_16x16x32_f16(a[i], bfr[jn], acc[i][jn], 0, 0, 0);
    }
    __syncthreads();
  }
  const float* bias = eb1 + (size_t)e * H_DIM;
#pragma unroll
  for (int nt = 0; nt < 4; ++nt) {
    int col = n0 + wn * 64 + nt * 16 + l16;
    float bb = bias[col];
#pragma unroll
    for (int mtile = 0; mtile < 4; ++mtile) {
#pragma unroll
      for (int r = 0; r < 4; ++r) {
        int rloc = wm * 64 + mtile * 16 + quad * 4 + r;
        float v = fmaxf(acc[mtile][nt][r] + bb, 0.f) * sC[rloc];
        EHS[(size_t)(slot0 + rloc) * K2 + (size_t)z * H_DIM + col] = f2h_bits(v);
      }
    }
  }
}

// ------- expert GEMM2 (routed): out[r] = ehs[slot] @ [w2_ea; w2_eb] + c_a*eb2_a + c_b*eb2_b --------
// K = 8192 contiguous per slot; single write per output row, no atomics.
__global__ __launch_bounds__(256) void k_expert_o(const unsigned short* __restrict__ EHS,
                                                  const unsigned short* __restrict__ W2T,
                                                  const float* __restrict__ combine,
                                                  const float* __restrict__ eb2,
                                                  const int* __restrict__ sorted,
                                                  const int* __restrict__ meta,
                                                  float* __restrict__ OUT) {
  const int mt = blockIdx.x;
  const int tb1 = meta[1], tb2 = meta[2], tb3 = meta[3];
  if (mt >= tb3) return;
  const int b = (mt >= tb2) ? 2 : (mt >= tb1) ? 1 : 0;
  int ea, ebx; bucket_experts(b, ea, ebx);
  const int slot0 = mt * 128;  // slot base == 128 * m-tile index (bases are tile-aligned)
  const int n0 = blockIdx.y * 128;

  __shared__ __align__(16) char smem[32768];
  __shared__ int sRow[128];
  __shared__ float sCa[128], sCb[128];
  char* sA = smem;
  char* sB = smem + 16384;
  const int t = threadIdx.x;
  if (t < 128) {
    int r = sorted[slot0 + t];
    sRow[t] = r;
    int rr = (r < 0) ? 0 : r;
    sCa[t] = combine[(size_t)rr * 3 + ea];
    sCb[t] = combine[(size_t)rr * 3 + ebx];
  }

  const unsigned short* ap[4];
  size_t bpo[4];
  int soff[4];
#pragma unroll
  for (int i = 0; i < 4; ++i) {
    int sa = t + i * 256;
    int row = sa >> 3;
    int j = (sa & 7) ^ (row & 7);
    soff[i] = sa * 16;
    ap[i] = EHS + (size_t)(slot0 + row) * K2 + j * 8;
    bpo[i] = (size_t)(n0 + row) * H_DIM + j * 8;
  }
  const int lane = t & 63;
  const int wm = (t >> 6) & 1, wn = t >> 7;
  const int quad = lane >> 4, l16 = lane & 15;
  int offA[4][2], offB[4][2];
#pragma unroll
  for (int mtile = 0; mtile < 4; ++mtile) {
    int ra = wm * 64 + mtile * 16 + l16;
    int rb = wn * 64 + mtile * 16 + l16;
#pragma unroll
    for (int s = 0; s < 2; ++s) {
      offA[mtile][s] = ra * 128 + (((s * 4 + quad) ^ (ra & 7)) * 16);
      offB[mtile][s] = rb * 128 + (((s * 4 + quad) ^ (rb & 7)) * 16);
    }
  }
  f4 acc[4][4] = {};
#pragma unroll
  for (int half = 0; half < 2; ++half) {
    const int e = half ? ebx : ea;
    const unsigned short* Bb = W2T + (size_t)e * O_DIM * H_DIM;
    const int ka = half * H_DIM;
    for (int k0 = 0; k0 < H_DIM; k0 += 64) {
#pragma unroll
      for (int i = 0; i < 4; ++i) {
        async16(ap[i] + ka + k0, sA + soff[i]);
        async16(Bb + bpo[i] + k0, sB + soff[i]);
      }
      __syncthreads();
#pragma unroll
      for (int s = 0; s < 2; ++s) {
        half8 a[4], bfr[4];
#pragma unroll
        for (int i = 0; i < 4; ++i) a[i] = *(const half8*)(sA + offA[i][s]);
#pragma unroll
        for (int i = 0; i < 4; ++i) bfr[i] = *(const half8*)(sB + offB[i][s]);
#pragma unroll
        for (int i = 0; i < 4; ++i)
#pragma unroll
          for (int jn = 0; jn < 4; ++jn)
            acc[i][jn] = __builtin_amdgcn_mfma_f32_16x16x32_f16(a[i], bfr[jn], acc[i][jn], 0, 0, 0);
      }
      __syncthreads();
    }
  }
#pragma unroll
  for (int nt = 0; nt < 4; ++nt) {
    int col = n0 + wn * 64 + nt * 16 + l16;
    float ba = eb2[(size_t)ea * O_DIM + col];
    float bb = eb2[(size_t)ebx * O_DIM + col];
#pragma unroll
    for (int mtile = 0; mtile < 4; ++mtile) {
#pragma unroll
      for (int r = 0; r < 4; ++r) {
        int rloc = wm * 64 + mtile * 16 + quad * 4 + r;
        int rowg = sRow[rloc];
        if (rowg >= 0) {
          float v = acc[mtile][nt][r] + sCa[rloc] * ba + sCb[rloc] * bb;
          OUT[(size_t)rowg * O_DIM + col] = v;
        }
      }
    }
  }
}

extern "C" void kernel_launch(void* const* d_in, const int* in_sizes, int n_in,
                              void* d_out, int out_size, void* d_ws, size_t ws_size,
                              hipStream_t stream) {
  const float* x   = (const float*)d_in[0];
  const float* gw1 = (const float*)d_in[1];
  const float* gb1 = (const float*)d_in[2];
  const float* gw2 = (const float*)d_in[3];
  const float* gb2 = (const float*)d_in[4];
  const float* gw3 = (const float*)d_in[5];
  const float* gb3 = (const float*)d_in[6];
  const float* ew1 = (const float*)d_in[7];
  const float* eb1 = (const float*)d_in[8];
  const float* ew2 = (const float*)d_in[9];
  const float* eb2 = (const float*)d_in[10];
  float* out = (float*)d_out;
  float* gates = out + (size_t)B_ROWS * O_DIM;

  char* ws = (char*)d_ws;
  size_t off = 0;
  auto take = [&](size_t bytes) -> char* {
    char* p = ws + off;
    off += (bytes + 255) & ~(size_t)255;
    return p;
  };
  unsigned short* xh  = (unsigned short*)take((size_t)B_ROWS * D_DIM * 2);        // 16.8 MB
  unsigned short* w1t = (unsigned short*)take((size_t)E_NUM * H_DIM * D_DIM * 2); // 25.2 MB
  unsigned short* w2t = (unsigned short*)take((size_t)E_NUM * O_DIM * H_DIM * 2); // 25.2 MB
  float* comb   = (float*)take((size_t)B_ROWS * 3 * 4);
  float* g1     = (float*)take((size_t)B_ROWS * 256 * 4);                         // 8.4 MB
  float* h2     = (float*)take((size_t)B_ROWS * 128 * 4);                         // 4.2 MB
  int* bucket   = (int*)take((size_t)B_ROWS * 4);
  int* sorted   = (int*)take((size_t)SLOT_MAX * 4);
  int* cnt      = (int*)take(3 * 4);
  int* cnt2     = (int*)take(3 * 4);
  int* meta     = (int*)take(4 * 4);
  unsigned short* ehs = (unsigned short*)take((size_t)SLOT_MAX * K2 * 2);         // 138.4 MB

  hipMemsetAsync(cnt, 0, 3 * 4, stream);
  hipMemsetAsync(sorted, 0xFF, (size_t)SLOT_MAX * 4, stream);  // pad slots = -1

  // precision-insensitive pre-pass: f16 casts/transposes
  k_cast_x<<<dim3(B_ROWS * D_DIM / (256 * 8)), 256, 0, stream>>>(x, xh);
  k_transpose_cast<<<dim3(H_DIM / 32, D_DIM / 32, E_NUM), 256, 0, stream>>>(ew1, w1t, D_DIM, H_DIM);
  k_transpose_cast<<<dim3(O_DIM / 32, H_DIM / 32, E_NUM), 256, 0, stream>>>(ew2, w2t, H_DIM, O_DIM);

  // gating in fp32 (top-k selection must track the fp32 reference)
  k_gemm_f32<<<dim3(256 / 64, B_ROWS / 64), 256, 0, stream>>>(x, gw1, gb1, g1, 256, D_DIM);
  k_gemm_f32<<<dim3(128 / 64, B_ROWS / 64), 256, 0, stream>>>(g1, gw2, gb2, h2, 128, 256);
  k_gate_topk<<<dim3(B_ROWS / 4), 256, 0, stream>>>(h2, gw3, gb3, gates, comb, bucket);

  // routing: bucket rows by excluded expert into 128-aligned sorted segments
  k_count<<<dim3(B_ROWS / 256), 256, 0, stream>>>(bucket, cnt);
  k_meta<<<1, 1, 0, stream>>>(cnt, meta, cnt2);
  k_scatter<<<dim3(B_ROWS / 256), 256, 0, stream>>>(bucket, meta, cnt2, sorted);

  // experts in f16 MFMA, routed (2/3 of dense FLOPs)
  k_expert_h<<<dim3(MT_MAX, H_DIM / 128, 2), 256, 0, stream>>>(
      xh, w1t, comb, eb1, sorted, meta, ehs);
  k_expert_o<<<dim3(MT_MAX, O_DIM / 128), 256, 0, stream>>>(
      ehs, w2t, comb, eb2, sorted, meta, out);
}